// Round 1
// baseline (1490.736 us; speedup 1.0000x reference)
//
#include <hip/hip_runtime.h>

// Problem constants (match reference)
constexpr int DIN  = 128;
constexpr int DOUT = 128;
constexpr float EPS_SCALE = 1e-7f;
constexpr float SLOPE = 0.01f;

__device__ __forceinline__ float lrelu(float x) { return x > 0.f ? x : SLOPE * x; }

// ---------------------------------------------------------------------------
// Edge kernel: 32 threads per edge, each thread handles 4 of the 128 dims.
//   e_d  = leaky( coeff . W_spatial[d,:] + b_spatial[d] )
//   s[dst,d] += feat[src,d] * e_d   (atomic)
//   deg[dst] += 1                   (atomic, lane 0)
// ---------------------------------------------------------------------------
__global__ __launch_bounds__(256) void edge_kernel(
    const float* __restrict__ feat,
    const float* __restrict__ pos,
    const int*   __restrict__ src,
    const int*   __restrict__ dst,
    const float* __restrict__ Wsp,   // [128][3] row-major
    const float* __restrict__ bsp,   // [128]
    float* __restrict__ s,           // [N][128]
    float* __restrict__ deg,         // [N]
    int E)
{
    long long t = (long long)blockIdx.x * blockDim.x + threadIdx.x;
    int e    = (int)(t >> 5);
    int lane = (int)(t & 31);
    if (e >= E) return;

    int sv = src[e];
    int dv = dst[e];

    float c0, c1, c2;
    if (lane == 0) {
        float r0 = pos[dv * 3 + 0] - pos[sv * 3 + 0];
        float r1 = pos[dv * 3 + 1] - pos[sv * 3 + 1];
        float r2 = pos[dv * 3 + 2] - pos[sv * 3 + 2];
        float sc = sqrtf(r0 * r0 + r1 * r1 + r2 * r2) + EPS_SCALE;
        float inv = 1.0f / sc;
        c0 = (r0 + 1.0f) * inv;
        c1 = (r1 + 1.0f) * inv;
        c2 = (r2 + 1.0f) * inv;
    }
    c0 = __shfl(c0, 0, 32);
    c1 = __shfl(c1, 0, 32);
    c2 = __shfl(c2, 0, 32);

    int d = lane * 4;                       // dims d..d+3
    // W_spatial rows d..d+3 = 12 contiguous floats, 16B-aligned (d*12B, d%4==0)
    const float4* w4 = (const float4*)(Wsp + d * 3);
    float4 wa = w4[0], wb = w4[1], wc = w4[2];
    float4 bv = *(const float4*)(bsp + d);
    float4 f  = *(const float4*)(feat + (long long)sv * DIN + d);

    float v0 = lrelu(fmaf(c0, wa.x, fmaf(c1, wa.y, fmaf(c2, wa.z, bv.x)))) * f.x;
    float v1 = lrelu(fmaf(c0, wa.w, fmaf(c1, wb.x, fmaf(c2, wb.y, bv.y)))) * f.y;
    float v2 = lrelu(fmaf(c0, wb.z, fmaf(c1, wb.w, fmaf(c2, wc.x, bv.z)))) * f.z;
    float v3 = lrelu(fmaf(c0, wc.y, fmaf(c1, wc.z, fmaf(c2, wc.w, bv.w)))) * f.w;

    float* sp = s + (long long)dv * DIN + d;
    atomicAdd(sp + 0, v0);
    atomicAdd(sp + 1, v1);
    atomicAdd(sp + 2, v2);
    atomicAdd(sp + 3, v3);
    if (lane == 0) atomicAdd(deg + dv, 1.0f);
}

// ---------------------------------------------------------------------------
// invdeg[i] = 1 / max(deg[i], 1)
// ---------------------------------------------------------------------------
__global__ void invdeg_kernel(const float* __restrict__ deg,
                              float* __restrict__ invdeg, int n)
{
    int i = blockIdx.x * blockDim.x + threadIdx.x;
    if (i < n) invdeg[i] = 1.0f / fmaxf(deg[i], 1.0f);
}

// ---------------------------------------------------------------------------
// Node kernel: fused dual GEMM + epilogue.
//   out[r][c] = leaky( feat[r,:]@W_self[c,:] + h_mean[r,:]@W_neigh[c,:]
//                      + b_self[c] + b_neigh[c] + bias[c] )
// Treated as [feat | h_mean] (K=256) @ [W_self ; W_neigh]^T.
// Block: 256 threads, 64 rows x 128 cols tile, 4x8 register blocking.
// K staged in 4 chunks of 64 into LDS (padded stride 68 -> <=2-way bank alias).
// ---------------------------------------------------------------------------
__global__ __launch_bounds__(256) void node_kernel(
    const float* __restrict__ feat,
    const float* __restrict__ s,        // raw segment sums [N][128]
    const float* __restrict__ invdeg,   // [N]
    const float* __restrict__ Wself,    // [128][128]
    const float* __restrict__ Wneigh,   // [128][128]
    const float* __restrict__ b_neigh,
    const float* __restrict__ b_self,
    const float* __restrict__ bias,
    float* __restrict__ out, int n)
{
    __shared__ float X[64][68];
    __shared__ float W[128][68];
    __shared__ float inv_s[64];

    int r0  = blockIdx.x * 64;
    int tid = threadIdx.x;
    int tx  = tid & 15;        // col group
    int ty  = tid >> 4;        // row group

    if (tid < 64) {
        int r = r0 + tid;
        inv_s[tid] = (r < n) ? invdeg[r] : 0.0f;
    }

    float acc[4][8];
#pragma unroll
    for (int i = 0; i < 4; ++i)
#pragma unroll
        for (int j = 0; j < 8; ++j) acc[i][j] = 0.0f;

    for (int kc = 0; kc < 4; ++kc) {
        int k0 = kc * 64;
        __syncthreads();   // also covers inv_s visibility on first iter

        // Stage X chunk: 64 rows x 64 k (1024 float4, 4 per thread)
#pragma unroll
        for (int q = 0; q < 4; ++q) {
            int idx = tid + 256 * q;
            int r   = idx >> 4;
            int kk  = (idx & 15) * 4;
            int gr  = r0 + r;
            float4 v = make_float4(0.f, 0.f, 0.f, 0.f);
            if (gr < n) {
                int k = k0 + kk;
                if (k < 128) {
                    v = *(const float4*)(feat + (long long)gr * DIN + k);
                } else {
                    v = *(const float4*)(s + (long long)gr * DIN + (k - 128));
                    float iv = inv_s[r];
                    v.x *= iv; v.y *= iv; v.z *= iv; v.w *= iv;
                }
            }
            X[r][kk + 0] = v.x; X[r][kk + 1] = v.y;
            X[r][kk + 2] = v.z; X[r][kk + 3] = v.w;
        }

        // Stage W chunk: 128 d x 64 k (2048 float4, 8 per thread)
#pragma unroll
        for (int q = 0; q < 8; ++q) {
            int idx = tid + 256 * q;
            int d   = idx >> 4;
            int kk  = (idx & 15) * 4;
            int k   = k0 + kk;
            float4 v;
            if (k < 128) v = *(const float4*)(Wself  + d * DIN + k);
            else         v = *(const float4*)(Wneigh + d * DIN + (k - 128));
            W[d][kk + 0] = v.x; W[d][kk + 1] = v.y;
            W[d][kk + 2] = v.z; W[d][kk + 3] = v.w;
        }
        __syncthreads();

#pragma unroll
        for (int k4 = 0; k4 < 16; ++k4) {
            float4 xv[4], wv[8];
#pragma unroll
            for (int i = 0; i < 4; ++i)
                xv[i] = *(const float4*)&X[ty + 16 * i][k4 * 4];
#pragma unroll
            for (int j = 0; j < 8; ++j)
                wv[j] = *(const float4*)&W[tx + 16 * j][k4 * 4];
#pragma unroll
            for (int i = 0; i < 4; ++i)
#pragma unroll
                for (int j = 0; j < 8; ++j) {
                    acc[i][j] = fmaf(xv[i].x, wv[j].x,
                                fmaf(xv[i].y, wv[j].y,
                                fmaf(xv[i].z, wv[j].z,
                                fmaf(xv[i].w, wv[j].w, acc[i][j]))));
                }
        }
    }

    // Epilogue
#pragma unroll
    for (int j = 0; j < 8; ++j) {
        int col = tx + 16 * j;
        float bb = b_neigh[col] + b_self[col] + bias[col];
#pragma unroll
        for (int i = 0; i < 4; ++i) {
            int r = r0 + ty + 16 * i;
            if (r < n) out[(long long)r * DOUT + col] = lrelu(acc[i][j] + bb);
        }
    }
}

// ---------------------------------------------------------------------------
extern "C" void kernel_launch(void* const* d_in, const int* in_sizes, int n_in,
                              void* d_out, int out_size, void* d_ws, size_t ws_size,
                              hipStream_t stream)
{
    const float* feat    = (const float*)d_in[0];
    const float* pos     = (const float*)d_in[1];
    const int*   src     = (const int*)  d_in[2];
    const int*   dst     = (const int*)  d_in[3];
    const float* Wsp     = (const float*)d_in[4];
    const float* bsp     = (const float*)d_in[5];
    const float* Wneigh  = (const float*)d_in[6];
    const float* b_neigh = (const float*)d_in[7];
    const float* Wself   = (const float*)d_in[8];
    const float* b_self  = (const float*)d_in[9];
    const float* bias    = (const float*)d_in[10];

    int N = in_sizes[0] / DIN;
    int E = in_sizes[2];

    // Workspace layout: s [N*128] | deg [N] | invdeg [N]   (floats)
    float* s      = (float*)d_ws;
    float* deg    = s + (size_t)N * DIN;
    float* invdeg = deg + N;

    // Zero s and deg
    hipMemsetAsync(d_ws, 0, ((size_t)N * DIN + N) * sizeof(float), stream);

    // Edge phase
    {
        long long threads = (long long)E * 32;
        int blocks = (int)((threads + 255) / 256);
        edge_kernel<<<blocks, 256, 0, stream>>>(feat, pos, src, dst, Wsp, bsp,
                                                s, deg, E);
    }

    // invdeg
    {
        int blocks = (N + 255) / 256;
        invdeg_kernel<<<blocks, 256, 0, stream>>>(deg, invdeg, N);
    }

    // Node phase (fused dual GEMM + epilogue)
    {
        int blocks = (N + 63) / 64;
        node_kernel<<<blocks, 256, 0, stream>>>(feat, s, invdeg, Wself, Wneigh,
                                                b_neigh, b_self, bias,
                                                (float*)d_out, N);
    }
}

// Round 2
// 349.404 us; speedup vs baseline: 4.2665x; 4.2665x over previous
//
#include <hip/hip_runtime.h>

constexpr int DIN  = 128;
constexpr int DOUT = 128;
constexpr float EPS_SCALE = 1e-7f;
constexpr float SLOPE = 0.01f;

__device__ __forceinline__ float lrelu(float x) { return x > 0.f ? x : SLOPE * x; }

// ---------------------------------------------------------------------------
// 1) Histogram of dst
// ---------------------------------------------------------------------------
__global__ __launch_bounds__(256) void hist_kernel(
    const int* __restrict__ dst, int* __restrict__ hist, int E)
{
    int e = blockIdx.x * blockDim.x + threadIdx.x;
    if (e < E) atomicAdd(&hist[dst[e]], 1);
}

// ---------------------------------------------------------------------------
// 2) Exclusive prefix sum (single block, 2-level: per-thread serial + block scan)
//    rowptr[0..N], rowptr[N] = E
// ---------------------------------------------------------------------------
__global__ __launch_bounds__(1024) void scan_kernel(
    const int* __restrict__ hist, int* __restrict__ rowptr, int N)
{
    __shared__ int sc[1024];
    int t = threadIdx.x;
    int chunk = (N + 1023) / 1024;
    int begin = t * chunk;
    int end   = min(begin + chunk, N);

    int sum = 0;
    for (int i = begin; i < end; ++i) sum += hist[i];
    sc[t] = sum;
    __syncthreads();

    // Hillis-Steele inclusive scan over 1024 partials
    for (int off = 1; off < 1024; off <<= 1) {
        int v = (t >= off) ? sc[t - off] : 0;
        __syncthreads();
        sc[t] += v;
        __syncthreads();
    }

    int run = (t > 0) ? sc[t - 1] : 0;   // exclusive base
    for (int i = begin; i < end; ++i) {
        rowptr[i] = run;
        run += hist[i];
    }
    if (t == 1023) rowptr[N] = sc[1023];
}

// ---------------------------------------------------------------------------
// 3) Scatter edge ids into CSR order (int atomics on L2-resident cursors)
// ---------------------------------------------------------------------------
__global__ __launch_bounds__(256) void scatter_kernel(
    const int* __restrict__ dst, const int* __restrict__ rowptr,
    int* __restrict__ cur, int* __restrict__ eid, int E)
{
    int e = blockIdx.x * blockDim.x + threadIdx.x;
    if (e < E) {
        int d = dst[e];
        int p = atomicAdd(&cur[d], 1);
        eid[rowptr[d] + p] = e;
    }
}

// ---------------------------------------------------------------------------
// 4) Gather-side reduction: 32 lanes per node, each lane owns 4 dims.
//    h_mean[v] = (1/max(deg,1)) * sum_{e in in(v)} feat[src(e)] * e(e)
//    written directly into d_out (reused as hm buffer by the GEMM).
// ---------------------------------------------------------------------------
__global__ __launch_bounds__(256) void gather_kernel(
    const float* __restrict__ feat,
    const float* __restrict__ pos,
    const int*   __restrict__ src,
    const int*   __restrict__ rowptr,
    const int*   __restrict__ eid,
    const float* __restrict__ Wsp,   // [128][3]
    const float* __restrict__ bsp,   // [128]
    float* __restrict__ hm,          // [N][128]  (aliases d_out)
    int N)
{
    int g    = threadIdx.x >> 5;
    int lane = threadIdx.x & 31;
    int v    = blockIdx.x * 8 + g;
    if (v >= N) return;

    int start = rowptr[v];
    int end   = rowptr[v + 1];

    float p0 = pos[v * 3 + 0];
    float p1 = pos[v * 3 + 1];
    float p2 = pos[v * 3 + 2];

    int d = lane * 4;
    const float4* w4 = (const float4*)(Wsp + d * 3);   // 16B aligned (d%4==0)
    float4 wa = w4[0], wb = w4[1], wc = w4[2];
    float4 bv = *(const float4*)(bsp + d);

    float a0 = 0.f, a1 = 0.f, a2 = 0.f, a3 = 0.f;

    for (int i = start; i < end; ++i) {
        int e  = eid[i];
        int sv = src[e];
        float r0 = p0 - pos[sv * 3 + 0];
        float r1 = p1 - pos[sv * 3 + 1];
        float r2 = p2 - pos[sv * 3 + 2];
        float inv = 1.0f / (sqrtf(r0 * r0 + r1 * r1 + r2 * r2) + EPS_SCALE);
        float c0 = (r0 + 1.0f) * inv;
        float c1 = (r1 + 1.0f) * inv;
        float c2 = (r2 + 1.0f) * inv;

        float4 f = *(const float4*)(feat + (long long)sv * DIN + d);

        a0 = fmaf(lrelu(fmaf(c0, wa.x, fmaf(c1, wa.y, fmaf(c2, wa.z, bv.x)))), f.x, a0);
        a1 = fmaf(lrelu(fmaf(c0, wa.w, fmaf(c1, wb.x, fmaf(c2, wb.y, bv.y)))), f.y, a1);
        a2 = fmaf(lrelu(fmaf(c0, wb.z, fmaf(c1, wb.w, fmaf(c2, wc.x, bv.z)))), f.z, a2);
        a3 = fmaf(lrelu(fmaf(c0, wc.y, fmaf(c1, wc.z, fmaf(c2, wc.w, bv.w)))), f.w, a3);
    }

    float invd = 1.0f / fmaxf((float)(end - start), 1.0f);
    float4 o = make_float4(a0 * invd, a1 * invd, a2 * invd, a3 * invd);
    *(float4*)(hm + (long long)v * DIN + d) = o;
}

// ---------------------------------------------------------------------------
// 5) Fused dual GEMM + epilogue.
//    out[r][c] = leaky( feat[r,:]@W_self[c,:] + hm[r,:]@W_neigh[c,:]
//                       + b_self[c] + b_neigh[c] + bias[c] )
//    hm aliases out: each block reads only its own 64 rows of hm, and all
//    reads (staging) complete before the epilogue writes those rows.
// ---------------------------------------------------------------------------
__global__ __launch_bounds__(256) void node_kernel(
    const float* __restrict__ feat,
    const float* __restrict__ hm,       // [N][128] (aliases out)
    const float* __restrict__ Wself,    // [128][128]
    const float* __restrict__ Wneigh,   // [128][128]
    const float* __restrict__ b_neigh,
    const float* __restrict__ b_self,
    const float* __restrict__ bias,
    float* __restrict__ out, int n)
{
    __shared__ float X[64][68];
    __shared__ float W[128][68];

    int r0  = blockIdx.x * 64;
    int tid = threadIdx.x;
    int tx  = tid & 15;        // col group
    int ty  = tid >> 4;        // row group

    float acc[4][8];
#pragma unroll
    for (int i = 0; i < 4; ++i)
#pragma unroll
        for (int j = 0; j < 8; ++j) acc[i][j] = 0.0f;

    for (int kc = 0; kc < 4; ++kc) {
        int k0 = kc * 64;
        __syncthreads();

        // Stage X chunk: 64 rows x 64 k
#pragma unroll
        for (int q = 0; q < 4; ++q) {
            int idx = tid + 256 * q;
            int r   = idx >> 4;
            int kk  = (idx & 15) * 4;
            int gr  = r0 + r;
            float4 v = make_float4(0.f, 0.f, 0.f, 0.f);
            if (gr < n) {
                int k = k0 + kk;
                if (k < 128) v = *(const float4*)(feat + (long long)gr * DIN + k);
                else         v = *(const float4*)(hm   + (long long)gr * DIN + (k - 128));
            }
            X[r][kk + 0] = v.x; X[r][kk + 1] = v.y;
            X[r][kk + 2] = v.z; X[r][kk + 3] = v.w;
        }

        // Stage W chunk: 128 d x 64 k
#pragma unroll
        for (int q = 0; q < 8; ++q) {
            int idx = tid + 256 * q;
            int dd  = idx >> 4;
            int kk  = (idx & 15) * 4;
            int k   = k0 + kk;
            float4 v;
            if (k < 128) v = *(const float4*)(Wself  + dd * DIN + k);
            else         v = *(const float4*)(Wneigh + dd * DIN + (k - 128));
            W[dd][kk + 0] = v.x; W[dd][kk + 1] = v.y;
            W[dd][kk + 2] = v.z; W[dd][kk + 3] = v.w;
        }
        __syncthreads();

#pragma unroll
        for (int k4 = 0; k4 < 16; ++k4) {
            float4 xv[4], wv[8];
#pragma unroll
            for (int i = 0; i < 4; ++i)
                xv[i] = *(const float4*)&X[ty + 16 * i][k4 * 4];
#pragma unroll
            for (int j = 0; j < 8; ++j)
                wv[j] = *(const float4*)&W[tx + 16 * j][k4 * 4];
#pragma unroll
            for (int i = 0; i < 4; ++i)
#pragma unroll
                for (int j = 0; j < 8; ++j) {
                    acc[i][j] = fmaf(xv[i].x, wv[j].x,
                                fmaf(xv[i].y, wv[j].y,
                                fmaf(xv[i].z, wv[j].z,
                                fmaf(xv[i].w, wv[j].w, acc[i][j]))));
                }
        }
    }

    // Epilogue
#pragma unroll
    for (int j = 0; j < 8; ++j) {
        int col = tx + 16 * j;
        float bb = b_neigh[col] + b_self[col] + bias[col];
#pragma unroll
        for (int i = 0; i < 4; ++i) {
            int r = r0 + ty + 16 * i;
            if (r < n) out[(long long)r * DOUT + col] = lrelu(acc[i][j] + bb);
        }
    }
}

// ---------------------------------------------------------------------------
extern "C" void kernel_launch(void* const* d_in, const int* in_sizes, int n_in,
                              void* d_out, int out_size, void* d_ws, size_t ws_size,
                              hipStream_t stream)
{
    const float* feat    = (const float*)d_in[0];
    const float* pos     = (const float*)d_in[1];
    const int*   src     = (const int*)  d_in[2];
    const int*   dst     = (const int*)  d_in[3];
    const float* Wsp     = (const float*)d_in[4];
    const float* bsp     = (const float*)d_in[5];
    const float* Wneigh  = (const float*)d_in[6];
    const float* b_neigh = (const float*)d_in[7];
    const float* Wself   = (const float*)d_in[8];
    const float* b_self  = (const float*)d_in[9];
    const float* bias    = (const float*)d_in[10];

    int N = in_sizes[0] / DIN;
    int E = in_sizes[2];

    // Workspace layout (ints): hist [N] | cur [N] | rowptr [N+1] | eid [E]
    int* hist   = (int*)d_ws;
    int* cur    = hist + N;
    int* rowptr = cur + N;
    int* eid    = rowptr + (N + 1);

    hipMemsetAsync(d_ws, 0, (size_t)2 * N * sizeof(int), stream);

    {
        int blocks = (E + 255) / 256;
        hist_kernel<<<blocks, 256, 0, stream>>>(dst, hist, E);
    }
    scan_kernel<<<1, 1024, 0, stream>>>(hist, rowptr, N);
    {
        int blocks = (E + 255) / 256;
        scatter_kernel<<<blocks, 256, 0, stream>>>(dst, rowptr, cur, eid, E);
    }

    float* hm = (float*)d_out;   // reuse output buffer for h_mean
    {
        int blocks = (N + 7) / 8;
        gather_kernel<<<blocks, 256, 0, stream>>>(feat, pos, src, rowptr, eid,
                                                  Wsp, bsp, hm, N);
    }
    {
        int blocks = (N + 63) / 64;
        node_kernel<<<blocks, 256, 0, stream>>>(feat, hm, Wself, Wneigh,
                                                b_neigh, b_self, bias,
                                                (float*)d_out, N);
    }
}

// Round 3
// 259.273 us; speedup vs baseline: 5.7497x; 1.3476x over previous
//
#include <hip/hip_runtime.h>

constexpr int DIN  = 128;
constexpr int DOUT = 128;
constexpr float EPS_SCALE = 1e-7f;
constexpr float SLOPE = 0.01f;

typedef __attribute__((ext_vector_type(8))) short bf16x8;
typedef __attribute__((ext_vector_type(4))) float f32x4;

__device__ __forceinline__ float lrelu(float x) { return x > 0.f ? x : SLOPE * x; }

__device__ __forceinline__ unsigned short f2bf(float x) {
    unsigned u = __float_as_uint(x);
    unsigned r = (u + 0x7FFFu + ((u >> 16) & 1u)) >> 16;   // RNE
    return (unsigned short)r;
}
__device__ __forceinline__ float bf2f(unsigned short h) {
    return __uint_as_float(((unsigned)h) << 16);
}

// ---------------------------------------------------------------------------
// 1) Histogram of dst
// ---------------------------------------------------------------------------
__global__ __launch_bounds__(256) void hist_kernel(
    const int* __restrict__ dst, int* __restrict__ hist, int E)
{
    int e = blockIdx.x * blockDim.x + threadIdx.x;
    if (e < E) atomicAdd(&hist[dst[e]], 1);
}

// ---------------------------------------------------------------------------
// 2) Exclusive prefix sum over hist -> rowptr[0..N]
// ---------------------------------------------------------------------------
__global__ __launch_bounds__(1024) void scan_kernel(
    const int* __restrict__ hist, int* __restrict__ rowptr, int N)
{
    __shared__ int sc[1024];
    int t = threadIdx.x;
    int chunk = (N + 1023) / 1024;
    int begin = t * chunk;
    int end   = min(begin + chunk, N);

    int sum = 0;
    for (int i = begin; i < end; ++i) sum += hist[i];
    sc[t] = sum;
    __syncthreads();

    for (int off = 1; off < 1024; off <<= 1) {
        int v = (t >= off) ? sc[t - off] : 0;
        __syncthreads();
        sc[t] += v;
        __syncthreads();
    }

    int run = (t > 0) ? sc[t - 1] : 0;
    for (int i = begin; i < end; ++i) {
        rowptr[i] = run;
        run += hist[i];
    }
    if (t == 1023) rowptr[N] = sc[1023];
}

// ---------------------------------------------------------------------------
// 3) Scatter src-node ids into CSR order (drops one indirection in gather)
// ---------------------------------------------------------------------------
__global__ __launch_bounds__(256) void scatter_kernel(
    const int* __restrict__ dst, const int* __restrict__ src,
    const int* __restrict__ rowptr, int* __restrict__ cur,
    int* __restrict__ srcid, int E)
{
    int e = blockIdx.x * blockDim.x + threadIdx.x;
    if (e < E) {
        int d = dst[e];
        int p = atomicAdd(&cur[d], 1);
        srcid[rowptr[d] + p] = src[e];
    }
}

// ---------------------------------------------------------------------------
// 4) feat fp32 -> bf16
// ---------------------------------------------------------------------------
__global__ __launch_bounds__(256) void convert_feat_kernel(
    const float* __restrict__ feat, unsigned short* __restrict__ featbf, int total4)
{
    int i = blockIdx.x * blockDim.x + threadIdx.x;   // handles 4 floats
    if (i < total4) {
        float4 v = *(const float4*)(feat + (size_t)i * 4);
        ushort4 o;
        o.x = f2bf(v.x); o.y = f2bf(v.y); o.z = f2bf(v.z); o.w = f2bf(v.w);
        *(ushort4*)(featbf + (size_t)i * 4) = o;
    }
}

// ---------------------------------------------------------------------------
// 5) Pack [W_self | W_neigh] into MFMA B-fragment order (bf16) + combined bias.
//    B frag for k-step s, col-frag f: lane l, elem j holds
//      Wc[col = f*16 + (l&15)][k = s*32 + (l>>4)*8 + j]
//    stored at bfrag[(((s*8+f)*64)+l)*8 + j]  (16B/lane contiguous loads)
// ---------------------------------------------------------------------------
__global__ __launch_bounds__(256) void pack_w_kernel(
    const float* __restrict__ Wself, const float* __restrict__ Wneigh,
    const float* __restrict__ b_self, const float* __restrict__ b_neigh,
    const float* __restrict__ bias,
    unsigned short* __restrict__ bfrag, float* __restrict__ bb)
{
    int idx = blockIdx.x * blockDim.x + threadIdx.x;   // 0..32767
    if (idx < 32768) {
        int j = idx & 7;
        int l = (idx >> 3) & 63;
        int f = (idx >> 9) & 7;
        int s = (idx >> 12) & 7;
        int k = s * 32 + ((l >> 4) << 3) + j;
        int c = f * 16 + (l & 15);
        float v = (k < 128) ? Wself[c * 128 + k] : Wneigh[c * 128 + (k - 128)];
        bfrag[idx] = f2bf(v);
    }
    if (idx < 128) bb[idx] = b_self[idx] + b_neigh[idx] + bias[idx];
}

// ---------------------------------------------------------------------------
// 6) Gather-side reduction. 64 lanes per node: 2 edges/iter, each 32-lane half
//    owns all 128 dims (4 per lane). Output h_mean as bf16.
// ---------------------------------------------------------------------------
__global__ __launch_bounds__(256) void gather_kernel(
    const unsigned short* __restrict__ featbf,
    const float* __restrict__ pos,
    const int*   __restrict__ rowptr,
    const int*   __restrict__ srcid,
    const float* __restrict__ Wsp,   // [128][3]
    const float* __restrict__ bsp,   // [128]
    unsigned short* __restrict__ hmbf,  // [N][128]
    int N)
{
    int g    = threadIdx.x >> 6;
    int lane = threadIdx.x & 63;
    int half = lane >> 5;
    int sl   = lane & 31;
    int v    = blockIdx.x * 4 + g;
    if (v >= N) return;

    int start = rowptr[v];
    int end   = rowptr[v + 1];

    float p0 = pos[v * 3 + 0];
    float p1 = pos[v * 3 + 1];
    float p2 = pos[v * 3 + 2];

    int d = sl * 4;
    const float4* w4 = (const float4*)(Wsp + d * 3);
    float4 wa = w4[0], wb = w4[1], wc = w4[2];
    float4 bv = *(const float4*)(bsp + d);

    float a0 = 0.f, a1 = 0.f, a2 = 0.f, a3 = 0.f;

    for (int i = start + half; i < end; i += 2) {
        int sv = srcid[i];
        float r0 = p0 - pos[sv * 3 + 0];
        float r1 = p1 - pos[sv * 3 + 1];
        float r2 = p2 - pos[sv * 3 + 2];
        float inv = 1.0f / (sqrtf(r0 * r0 + r1 * r1 + r2 * r2) + EPS_SCALE);
        float c0 = (r0 + 1.0f) * inv;
        float c1 = (r1 + 1.0f) * inv;
        float c2 = (r2 + 1.0f) * inv;

        ushort4 fq = *(const ushort4*)(featbf + (size_t)sv * DIN + d);
        float f0 = bf2f(fq.x), f1 = bf2f(fq.y), f2v = bf2f(fq.z), f3 = bf2f(fq.w);

        a0 = fmaf(lrelu(fmaf(c0, wa.x, fmaf(c1, wa.y, fmaf(c2, wa.z, bv.x)))), f0, a0);
        a1 = fmaf(lrelu(fmaf(c0, wa.w, fmaf(c1, wb.x, fmaf(c2, wb.y, bv.y)))), f1, a1);
        a2 = fmaf(lrelu(fmaf(c0, wb.z, fmaf(c1, wb.w, fmaf(c2, wc.x, bv.z)))), f2v, a2);
        a3 = fmaf(lrelu(fmaf(c0, wc.y, fmaf(c1, wc.z, fmaf(c2, wc.w, bv.w)))), f3, a3);
    }

    // combine the two halves
    a0 += __shfl_xor(a0, 32);
    a1 += __shfl_xor(a1, 32);
    a2 += __shfl_xor(a2, 32);
    a3 += __shfl_xor(a3, 32);

    if (half == 0) {
        float invd = 1.0f / fmaxf((float)(end - start), 1.0f);
        ushort4 o;
        o.x = f2bf(a0 * invd); o.y = f2bf(a1 * invd);
        o.z = f2bf(a2 * invd); o.w = f2bf(a3 * invd);
        *(ushort4*)(hmbf + (size_t)v * DIN + d) = o;
    }
}

// ---------------------------------------------------------------------------
// 7) Node GEMM via MFMA: out = lrelu([featbf | hmbf] @ Wc^T + bb)
//    Block = 4 waves, wave = 16 rows x 128 cols, K = 256 (8 steps of 32).
//    No LDS, no barriers; B frags stream from L2.
// ---------------------------------------------------------------------------
__global__ __launch_bounds__(256) void node_mfma_kernel(
    const unsigned short* __restrict__ featbf,
    const unsigned short* __restrict__ hmbf,
    const unsigned short* __restrict__ bfrag,
    const float* __restrict__ bb,
    float* __restrict__ out, int N)
{
    int wave = threadIdx.x >> 6;
    int lane = threadIdx.x & 63;
    int r0   = blockIdx.x * 64 + wave * 16;
    int row  = r0 + (lane & 15);
    bool rowok = row < N;
    int kb = (lane >> 4) << 3;            // k sub-offset within 32-step

    f32x4 acc[8];
#pragma unroll
    for (int f = 0; f < 8; ++f) acc[f] = (f32x4)0.0f;

#pragma unroll
    for (int s = 0; s < 8; ++s) {
        bf16x8 a = (bf16x8)(short)0;
        if (rowok) {
            const unsigned short* base =
                (s < 4 ? featbf : hmbf) + (size_t)row * DIN + (s & 3) * 32 + kb;
            a = *(const bf16x8*)base;
        }
#pragma unroll
        for (int f = 0; f < 8; ++f) {
            bf16x8 b = *(const bf16x8*)(bfrag + ((((s * 8 + f) * 64) + lane) * 8));
            acc[f] = __builtin_amdgcn_mfma_f32_16x16x32_bf16(a, b, acc[f], 0, 0, 0);
        }
    }

    // Epilogue: C/D layout col = lane&15, row = (lane>>4)*4 + reg
    int crow = r0 + ((lane >> 4) << 2);
    int col  = lane & 15;
#pragma unroll
    for (int f = 0; f < 8; ++f) {
        int c = f * 16 + col;
        float bbv = bb[c];
#pragma unroll
        for (int r = 0; r < 4; ++r) {
            int rr = crow + r;
            if (rr < N) out[(size_t)rr * DOUT + c] = lrelu(acc[f][r] + bbv);
        }
    }
}

// ---------------------------------------------------------------------------
extern "C" void kernel_launch(void* const* d_in, const int* in_sizes, int n_in,
                              void* d_out, int out_size, void* d_ws, size_t ws_size,
                              hipStream_t stream)
{
    const float* feat    = (const float*)d_in[0];
    const float* pos     = (const float*)d_in[1];
    const int*   src     = (const int*)  d_in[2];
    const int*   dst     = (const int*)  d_in[3];
    const float* Wsp     = (const float*)d_in[4];
    const float* bsp     = (const float*)d_in[5];
    const float* Wneigh  = (const float*)d_in[6];
    const float* b_neigh = (const float*)d_in[7];
    const float* Wself   = (const float*)d_in[8];
    const float* b_self  = (const float*)d_in[9];
    const float* bias    = (const float*)d_in[10];

    int N = in_sizes[0] / DIN;
    int E = in_sizes[2];

    // Workspace layout (16B-aligned chunks):
    // featbf [N*128 u16] | hmbf [N*128 u16] | bfrag [32768 u16] | bb [128 f32]
    // | hist [N] | cur [N] | srcid [E] | rowptr [N+1]
    char* p = (char*)d_ws;
    unsigned short* featbf = (unsigned short*)p; p += (size_t)N * DIN * 2;
    unsigned short* hmbf   = (unsigned short*)p; p += (size_t)N * DIN * 2;
    unsigned short* bfrag  = (unsigned short*)p; p += 32768 * 2;
    float* bb              = (float*)p;          p += 128 * 4;
    int* hist              = (int*)p;            p += (size_t)N * 4;
    int* cur               = (int*)p;            p += (size_t)N * 4;
    int* srcid             = (int*)p;            p += (size_t)E * 4;
    int* rowptr            = (int*)p;

    // zero hist + cur (adjacent)
    hipMemsetAsync(hist, 0, (size_t)2 * N * sizeof(int), stream);

    int eb = (E + 255) / 256;
    hist_kernel<<<eb, 256, 0, stream>>>(dst, hist, E);
    scan_kernel<<<1, 1024, 0, stream>>>(hist, rowptr, N);
    scatter_kernel<<<eb, 256, 0, stream>>>(dst, src, rowptr, cur, srcid, E);

    convert_feat_kernel<<<(N * 32 + 255) / 256, 256, 0, stream>>>(
        feat, featbf, N * 32);
    pack_w_kernel<<<128, 256, 0, stream>>>(Wself, Wneigh, b_self, b_neigh, bias,
                                           bfrag, bb);

    gather_kernel<<<(N + 3) / 4, 256, 0, stream>>>(featbf, pos, rowptr, srcid,
                                                   Wsp, bsp, hmbf, N);

    node_mfma_kernel<<<(N + 63) / 64, 256, 0, stream>>>(featbf, hmbf, bfrag, bb,
                                                        (float*)d_out, N);
}

// Round 4
// 193.506 us; speedup vs baseline: 7.7038x; 1.3399x over previous
//
#include <hip/hip_runtime.h>

constexpr int DIN  = 128;
constexpr int DOUT = 128;
constexpr float EPS_SCALE = 1e-7f;
constexpr float SLOPE = 0.01f;

typedef __attribute__((ext_vector_type(8))) short bf16x8;
typedef __attribute__((ext_vector_type(4))) float f32x4;

__device__ __forceinline__ float lrelu(float x) { return x > 0.f ? x : SLOPE * x; }

__device__ __forceinline__ unsigned short f2bf(float x) {
    unsigned u = __float_as_uint(x);
    unsigned r = (u + 0x7FFFu + ((u >> 16) & 1u)) >> 16;   // RNE
    return (unsigned short)r;
}
__device__ __forceinline__ float bf2f(unsigned short h) {
    return __uint_as_float(((unsigned)h) << 16);
}

// ---------------------------------------------------------------------------
// 1) Histogram of dst
// ---------------------------------------------------------------------------
__global__ __launch_bounds__(256) void hist_kernel(
    const int* __restrict__ dst, int* __restrict__ hist, int E)
{
    int e = blockIdx.x * blockDim.x + threadIdx.x;
    if (e < E) atomicAdd(&hist[dst[e]], 1);
}

// ---------------------------------------------------------------------------
// 2a) Per-block partial sums over 1024-elem chunks (int4 loads, N % 4 == 0)
// ---------------------------------------------------------------------------
__global__ __launch_bounds__(256) void scan_part1(
    const int* __restrict__ hist, int* __restrict__ bsum, int N)
{
    __shared__ int wsum[4];
    int tid = threadIdx.x, wave = tid >> 6, lane = tid & 63;
    int idx = blockIdx.x * 1024 + tid * 4;
    int4 h = make_int4(0, 0, 0, 0);
    if (idx < N) h = *(const int4*)(hist + idx);
    int s = h.x + h.y + h.z + h.w;
#pragma unroll
    for (int off = 1; off < 64; off <<= 1) s += __shfl_xor(s, off, 64);
    if (lane == 0) wsum[wave] = s;
    __syncthreads();
    if (tid == 0) bsum[blockIdx.x] = wsum[0] + wsum[1] + wsum[2] + wsum[3];
}

// ---------------------------------------------------------------------------
// 2b) Exclusive scan of <=64 block partials (1 wave); also rowptr[N] = E
// ---------------------------------------------------------------------------
__global__ __launch_bounds__(64) void scan_part2(
    const int* __restrict__ bsum, int* __restrict__ bbase, int nb,
    int* __restrict__ rowptr, int N, int E)
{
    int lane = threadIdx.x;
    int x = (lane < nb) ? bsum[lane] : 0;
    int orig = x;
#pragma unroll
    for (int off = 1; off < 64; off <<= 1) {
        int v = __shfl_up(x, off, 64);
        if (lane >= off) x += v;
    }
    if (lane < nb) bbase[lane] = x - orig;
    if (lane == 0) rowptr[N] = E;
}

// ---------------------------------------------------------------------------
// 2c) In-block exclusive scan + block base -> rowptr[0..N-1]
// ---------------------------------------------------------------------------
__global__ __launch_bounds__(256) void scan_part3(
    const int* __restrict__ hist, const int* __restrict__ bbase,
    int* __restrict__ rowptr, int N)
{
    __shared__ int wsum[4];
    int tid = threadIdx.x, wave = tid >> 6, lane = tid & 63;
    int idx = blockIdx.x * 1024 + tid * 4;
    int4 h = make_int4(0, 0, 0, 0);
    if (idx < N) h = *(const int4*)(hist + idx);
    int s = h.x + h.y + h.z + h.w;
    int x = s;
#pragma unroll
    for (int off = 1; off < 64; off <<= 1) {
        int v = __shfl_up(x, off, 64);
        if (lane >= off) x += v;
    }
    if (lane == 63) wsum[wave] = x;
    __syncthreads();
    int wb = 0;
#pragma unroll
    for (int w = 0; w < 4; ++w) if (w < wave) wb += wsum[w];
    int base = bbase[blockIdx.x] + wb + (x - s);
    if (idx < N) {
        rowptr[idx + 0] = base;
        rowptr[idx + 1] = base + h.x;
        rowptr[idx + 2] = base + h.x + h.y;
        rowptr[idx + 3] = base + h.x + h.y + h.z;
    }
}

// ---------------------------------------------------------------------------
// 3) Scatter src-node ids into CSR order
// ---------------------------------------------------------------------------
__global__ __launch_bounds__(256) void scatter_kernel(
    const int* __restrict__ dst, const int* __restrict__ src,
    const int* __restrict__ rowptr, int* __restrict__ cur,
    int* __restrict__ srcid, int E)
{
    int e = blockIdx.x * blockDim.x + threadIdx.x;
    if (e < E) {
        int d = dst[e];
        int p = atomicAdd(&cur[d], 1);
        srcid[rowptr[d] + p] = src[e];
    }
}

// ---------------------------------------------------------------------------
// 4) feat fp32 -> bf16
// ---------------------------------------------------------------------------
__global__ __launch_bounds__(256) void convert_feat_kernel(
    const float* __restrict__ feat, unsigned short* __restrict__ featbf, int total4)
{
    int i = blockIdx.x * blockDim.x + threadIdx.x;   // handles 4 floats
    if (i < total4) {
        float4 v = *(const float4*)(feat + (size_t)i * 4);
        ushort4 o;
        o.x = f2bf(v.x); o.y = f2bf(v.y); o.z = f2bf(v.z); o.w = f2bf(v.w);
        *(ushort4*)(featbf + (size_t)i * 4) = o;
    }
}

// ---------------------------------------------------------------------------
// 5) Pack [W_self | W_neigh] into MFMA B-fragment order (bf16) + combined bias.
//    B frag for k-step s, col-frag f: lane l, elem j holds
//      Wc[col = f*16 + (l&15)][k = s*32 + (l>>4)*8 + j]
// ---------------------------------------------------------------------------
__global__ __launch_bounds__(256) void pack_w_kernel(
    const float* __restrict__ Wself, const float* __restrict__ Wneigh,
    const float* __restrict__ b_self, const float* __restrict__ b_neigh,
    const float* __restrict__ bias,
    unsigned short* __restrict__ bfrag, float* __restrict__ bb)
{
    int idx = blockIdx.x * blockDim.x + threadIdx.x;   // 0..32767
    if (idx < 32768) {
        int j = idx & 7;
        int l = (idx >> 3) & 63;
        int f = (idx >> 9) & 7;
        int s = (idx >> 12) & 7;
        int k = s * 32 + ((l >> 4) << 3) + j;
        int c = f * 16 + (l & 15);
        float v = (k < 128) ? Wself[c * 128 + k] : Wneigh[c * 128 + (k - 128)];
        bfrag[idx] = f2bf(v);
    }
    if (idx < 128) bb[idx] = b_self[idx] + b_neigh[idx] + bias[idx];
}

// ---------------------------------------------------------------------------
// 6) Gather-side reduction. 1 wave per node, 4 edges in flight:
//    quarter q = lane>>4 owns edge i = start+q (step 4); sl = lane&15 owns
//    dims sl*8 .. sl*8+7 (bf16x8 = 16B feat loads). shfl_xor(16,32) reduce.
// ---------------------------------------------------------------------------
__global__ __launch_bounds__(256) void gather_kernel(
    const unsigned short* __restrict__ featbf,
    const float* __restrict__ pos,
    const int*   __restrict__ rowptr,
    const int*   __restrict__ srcid,
    const float* __restrict__ Wsp,   // [128][3]
    const float* __restrict__ bsp,   // [128]
    unsigned short* __restrict__ hmbf,  // [N][128]
    int N)
{
    int wid  = threadIdx.x >> 6;
    int lane = threadIdx.x & 63;
    int q    = lane >> 4;
    int sl   = lane & 15;
    int v    = blockIdx.x * 4 + wid;
    if (v >= N) return;

    int start = rowptr[v];
    int end   = rowptr[v + 1];

    float p0 = pos[v * 3 + 0];
    float p1 = pos[v * 3 + 1];
    float p2 = pos[v * 3 + 2];

    int d = sl * 8;
    // W rows d..d+7 = 24 consecutive floats at Wsp + d*3 (16B aligned: d*12B, d%8==0)
    float wv[24];
    {
        const float4* w4 = (const float4*)(Wsp + d * 3);
#pragma unroll
        for (int t = 0; t < 6; ++t) *(float4*)&wv[t * 4] = w4[t];
    }
    float bvv[8];
    *(float4*)&bvv[0] = *(const float4*)(bsp + d);
    *(float4*)&bvv[4] = *(const float4*)(bsp + d + 4);

    float a[8];
#pragma unroll
    for (int j = 0; j < 8; ++j) a[j] = 0.f;

    for (int i = start + q; i < end; i += 4) {
        int sv = srcid[i];
        float r0 = p0 - pos[sv * 3 + 0];
        float r1 = p1 - pos[sv * 3 + 1];
        float r2 = p2 - pos[sv * 3 + 2];
        float inv = 1.0f / (sqrtf(r0 * r0 + r1 * r1 + r2 * r2) + EPS_SCALE);
        float c0 = (r0 + 1.0f) * inv;
        float c1 = (r1 + 1.0f) * inv;
        float c2 = (r2 + 1.0f) * inv;

        bf16x8 f = *(const bf16x8*)(featbf + (size_t)sv * DIN + d);
#pragma unroll
        for (int j = 0; j < 8; ++j) {
            float e = lrelu(fmaf(c0, wv[j * 3 + 0],
                            fmaf(c1, wv[j * 3 + 1],
                            fmaf(c2, wv[j * 3 + 2], bvv[j]))));
            a[j] = fmaf(e, bf2f((unsigned short)f[j]), a[j]);
        }
    }

    // combine the four quarters
#pragma unroll
    for (int j = 0; j < 8; ++j) {
        a[j] += __shfl_xor(a[j], 16);
        a[j] += __shfl_xor(a[j], 32);
    }

    if (q == 0) {
        float invd = 1.0f / fmaxf((float)(end - start), 1.0f);
        bf16x8 o;
#pragma unroll
        for (int j = 0; j < 8; ++j) o[j] = (short)f2bf(a[j] * invd);
        *(bf16x8*)(hmbf + (size_t)v * DIN + d) = o;
    }
}

// ---------------------------------------------------------------------------
// 7) Node GEMM via MFMA: out = lrelu([featbf | hmbf] @ Wc^T + bb)
//    Block = 4 waves, wave = 16 rows x 128 cols, K = 256 (8 steps of 32).
// ---------------------------------------------------------------------------
__global__ __launch_bounds__(256) void node_mfma_kernel(
    const unsigned short* __restrict__ featbf,
    const unsigned short* __restrict__ hmbf,
    const unsigned short* __restrict__ bfrag,
    const float* __restrict__ bb,
    float* __restrict__ out, int N)
{
    int wave = threadIdx.x >> 6;
    int lane = threadIdx.x & 63;
    int r0   = blockIdx.x * 64 + wave * 16;
    int row  = r0 + (lane & 15);
    bool rowok = row < N;
    int kb = (lane >> 4) << 3;            // k sub-offset within 32-step

    f32x4 acc[8];
#pragma unroll
    for (int f = 0; f < 8; ++f) acc[f] = (f32x4)0.0f;

#pragma unroll
    for (int s = 0; s < 8; ++s) {
        bf16x8 a = (bf16x8)(short)0;
        if (rowok) {
            const unsigned short* base =
                (s < 4 ? featbf : hmbf) + (size_t)row * DIN + (s & 3) * 32 + kb;
            a = *(const bf16x8*)base;
        }
#pragma unroll
        for (int f = 0; f < 8; ++f) {
            bf16x8 b = *(const bf16x8*)(bfrag + ((((s * 8 + f) * 64) + lane) * 8));
            acc[f] = __builtin_amdgcn_mfma_f32_16x16x32_bf16(a, b, acc[f], 0, 0, 0);
        }
    }

    // Epilogue: C/D layout col = lane&15, row = (lane>>4)*4 + reg
    int crow = r0 + ((lane >> 4) << 2);
    int col  = lane & 15;
#pragma unroll
    for (int f = 0; f < 8; ++f) {
        int c = f * 16 + col;
        float bbv = bb[c];
#pragma unroll
        for (int r = 0; r < 4; ++r) {
            int rr = crow + r;
            if (rr < N) out[(size_t)rr * DOUT + c] = lrelu(acc[f][r] + bbv);
        }
    }
}

// ---------------------------------------------------------------------------
extern "C" void kernel_launch(void* const* d_in, const int* in_sizes, int n_in,
                              void* d_out, int out_size, void* d_ws, size_t ws_size,
                              hipStream_t stream)
{
    const float* feat    = (const float*)d_in[0];
    const float* pos     = (const float*)d_in[1];
    const int*   src     = (const int*)  d_in[2];
    const int*   dst     = (const int*)  d_in[3];
    const float* Wsp     = (const float*)d_in[4];
    const float* bsp     = (const float*)d_in[5];
    const float* Wneigh  = (const float*)d_in[6];
    const float* b_neigh = (const float*)d_in[7];
    const float* Wself   = (const float*)d_in[8];
    const float* b_self  = (const float*)d_in[9];
    const float* bias    = (const float*)d_in[10];

    int N = in_sizes[0] / DIN;
    int E = in_sizes[2];
    int nb = (N + 1023) / 1024;   // scan blocks (49 for N=50000; must be <= 64)

    // Workspace layout:
    // featbf [N*128 u16] | hmbf [N*128 u16] | bfrag [32768 u16] | bb [128 f32]
    // | hist [N] | cur [N] | srcid [E] | rowptr [N+4] | bsum [64] | bbase [64]
    char* p = (char*)d_ws;
    unsigned short* featbf = (unsigned short*)p; p += (size_t)N * DIN * 2;
    unsigned short* hmbf   = (unsigned short*)p; p += (size_t)N * DIN * 2;
    unsigned short* bfrag  = (unsigned short*)p; p += 32768 * 2;
    float* bb              = (float*)p;          p += 128 * 4;
    int* hist              = (int*)p;            p += (size_t)N * 4;
    int* cur               = (int*)p;            p += (size_t)N * 4;
    int* srcid             = (int*)p;            p += (size_t)E * 4;
    int* rowptr            = (int*)p;            p += (size_t)(N + 4) * 4;
    int* bsum              = (int*)p;            p += 64 * 4;
    int* bbase             = (int*)p;

    // zero hist + cur (adjacent)
    hipMemsetAsync(hist, 0, (size_t)2 * N * sizeof(int), stream);

    int eb = (E + 255) / 256;
    hist_kernel<<<eb, 256, 0, stream>>>(dst, hist, E);
    scan_part1<<<nb, 256, 0, stream>>>(hist, bsum, N);
    scan_part2<<<1, 64, 0, stream>>>(bsum, bbase, nb, rowptr, N, E);
    scan_part3<<<nb, 256, 0, stream>>>(hist, bbase, rowptr, N);
    scatter_kernel<<<eb, 256, 0, stream>>>(dst, src, rowptr, cur, srcid, E);

    convert_feat_kernel<<<(N * 32 + 255) / 256, 256, 0, stream>>>(
        feat, featbf, N * 32);
    pack_w_kernel<<<128, 256, 0, stream>>>(Wself, Wneigh, b_self, b_neigh, bias,
                                           bfrag, bb);

    gather_kernel<<<(N + 3) / 4, 256, 0, stream>>>(featbf, pos, rowptr, srcid,
                                                   Wsp, bsp, hmbf, N);

    node_mfma_kernel<<<(N + 63) / 64, 256, 0, stream>>>(featbf, hmbf, bfrag, bb,
                                                        (float*)d_out, N);
}

// Round 5
// 165.494 us; speedup vs baseline: 9.0078x; 1.1693x over previous
//
#include <hip/hip_runtime.h>

constexpr int DIN  = 128;
constexpr int DOUT = 128;
constexpr float EPS_SCALE = 1e-7f;

typedef __attribute__((ext_vector_type(8))) short bf16x8;
typedef __attribute__((ext_vector_type(4))) float f32x4;

__device__ __forceinline__ float lrelu(float x) { return fmaxf(x, 0.01f * x); }

__device__ __forceinline__ unsigned short f2bf(float x) {
    unsigned u = __float_as_uint(x);
    unsigned r = (u + 0x7FFFu + ((u >> 16) & 1u)) >> 16;   // RNE
    return (unsigned short)r;
}
__device__ __forceinline__ float bf2f(unsigned short h) {
    return __uint_as_float(((unsigned)h) << 16);
}

// ---------------------------------------------------------------------------
// 1) Fused prep: hist(dst) | feat fp32->bf16 | pack W frags + combined bias.
//    Independent work partitioned by blockIdx.
// ---------------------------------------------------------------------------
__global__ __launch_bounds__(256) void prep_kernel(
    const int* __restrict__ dst, int* __restrict__ hist, int E, int eb,
    const float* __restrict__ feat, unsigned short* __restrict__ featbf,
    int total8, int cb,
    const float* __restrict__ Wself, const float* __restrict__ Wneigh,
    const float* __restrict__ b_self, const float* __restrict__ b_neigh,
    const float* __restrict__ bias,
    unsigned short* __restrict__ bfrag, float* __restrict__ bb)
{
    int b = blockIdx.x;
    int tid = threadIdx.x;
    if (b < eb) {
        int e = b * 256 + tid;
        if (e < E) atomicAdd(&hist[dst[e]], 1);
    } else if (b < eb + cb) {
        int i = (b - eb) * 256 + tid;          // handles 8 floats
        if (i < total8) {
            float4 v0 = *(const float4*)(feat + (size_t)i * 8);
            float4 v1 = *(const float4*)(feat + (size_t)i * 8 + 4);
            bf16x8 o;
            o[0] = (short)f2bf(v0.x); o[1] = (short)f2bf(v0.y);
            o[2] = (short)f2bf(v0.z); o[3] = (short)f2bf(v0.w);
            o[4] = (short)f2bf(v1.x); o[5] = (short)f2bf(v1.y);
            o[6] = (short)f2bf(v1.z); o[7] = (short)f2bf(v1.w);
            *(bf16x8*)(featbf + (size_t)i * 8) = o;
        }
    } else {
        int idx = (b - eb - cb) * 256 + tid;   // 0..32767
        if (idx < 32768) {
            int j = idx & 7;
            int l = (idx >> 3) & 63;
            int f = (idx >> 9) & 7;
            int s = (idx >> 12) & 7;
            int k = s * 32 + ((l >> 4) << 3) + j;
            int c = f * 16 + (l & 15);
            float v = (k < 128) ? Wself[c * 128 + k] : Wneigh[c * 128 + (k - 128)];
            bfrag[idx] = f2bf(v);
        }
        if (idx < 128) bb[idx] = b_self[idx] + b_neigh[idx] + bias[idx];
    }
}

// ---------------------------------------------------------------------------
// 2a) Per-block partial sums over 1024-elem chunks
// ---------------------------------------------------------------------------
__global__ __launch_bounds__(256) void scan_part1(
    const int* __restrict__ hist, int* __restrict__ bsum, int N)
{
    __shared__ int wsum[4];
    int tid = threadIdx.x, wave = tid >> 6, lane = tid & 63;
    int idx = blockIdx.x * 1024 + tid * 4;
    int4 h = make_int4(0, 0, 0, 0);
    if (idx < N) h = *(const int4*)(hist + idx);
    int s = h.x + h.y + h.z + h.w;
#pragma unroll
    for (int off = 1; off < 64; off <<= 1) s += __shfl_xor(s, off, 64);
    if (lane == 0) wsum[wave] = s;
    __syncthreads();
    if (tid == 0) bsum[blockIdx.x] = wsum[0] + wsum[1] + wsum[2] + wsum[3];
}

// ---------------------------------------------------------------------------
// 2b) Exclusive scan of <=64 block partials; rowptr[N] = E
// ---------------------------------------------------------------------------
__global__ __launch_bounds__(64) void scan_part2(
    const int* __restrict__ bsum, int* __restrict__ bbase, int nb,
    int* __restrict__ rowptr, int N, int E)
{
    int lane = threadIdx.x;
    int x = (lane < nb) ? bsum[lane] : 0;
    int orig = x;
#pragma unroll
    for (int off = 1; off < 64; off <<= 1) {
        int v = __shfl_up(x, off, 64);
        if (lane >= off) x += v;
    }
    if (lane < nb) bbase[lane] = x - orig;
    if (lane == 0) rowptr[N] = E;
}

// ---------------------------------------------------------------------------
// 2c) In-block exclusive scan + block base -> rowptr[0..N-1]
// ---------------------------------------------------------------------------
__global__ __launch_bounds__(256) void scan_part3(
    const int* __restrict__ hist, const int* __restrict__ bbase,
    int* __restrict__ rowptr, int N)
{
    __shared__ int wsum[4];
    int tid = threadIdx.x, wave = tid >> 6, lane = tid & 63;
    int idx = blockIdx.x * 1024 + tid * 4;
    int4 h = make_int4(0, 0, 0, 0);
    if (idx < N) h = *(const int4*)(hist + idx);
    int s = h.x + h.y + h.z + h.w;
    int x = s;
#pragma unroll
    for (int off = 1; off < 64; off <<= 1) {
        int v = __shfl_up(x, off, 64);
        if (lane >= off) x += v;
    }
    if (lane == 63) wsum[wave] = x;
    __syncthreads();
    int wb = 0;
#pragma unroll
    for (int w = 0; w < 4; ++w) if (w < wave) wb += wsum[w];
    int base = bbase[blockIdx.x] + wb + (x - s);
    if (idx < N) {
        rowptr[idx + 0] = base;
        rowptr[idx + 1] = base + h.x;
        rowptr[idx + 2] = base + h.x + h.y;
        rowptr[idx + 3] = base + h.x + h.y + h.z;
    }
}

// ---------------------------------------------------------------------------
// 3) Scatter: compute per-edge spatial coeff + pack src id, in CSR order.
//    ecoef[slot] = {c0, c1, c2, bitcast(src)}
// ---------------------------------------------------------------------------
__global__ __launch_bounds__(256) void scatter_kernel(
    const int* __restrict__ dst, const int* __restrict__ src,
    const float* __restrict__ pos,
    const int* __restrict__ rowptr, int* __restrict__ cur,
    float4* __restrict__ ecoef, int E)
{
    int e = blockIdx.x * blockDim.x + threadIdx.x;
    if (e < E) {
        int d = dst[e];
        int s = src[e];
        float r0 = pos[d * 3 + 0] - pos[s * 3 + 0];
        float r1 = pos[d * 3 + 1] - pos[s * 3 + 1];
        float r2 = pos[d * 3 + 2] - pos[s * 3 + 2];
        float inv = 1.0f / (sqrtf(r0 * r0 + r1 * r1 + r2 * r2) + EPS_SCALE);
        int p = atomicAdd(&cur[d], 1);
        ecoef[rowptr[d] + p] = make_float4((r0 + 1.0f) * inv, (r1 + 1.0f) * inv,
                                           (r2 + 1.0f) * inv, __int_as_float(s));
    }
}

// ---------------------------------------------------------------------------
// 4) Gather: persistent waves, W_spatial/bias resident in registers.
//    Wave per node (grid-stride); quarter q owns edges start+q (step 4);
//    sl = lane&15 owns dims sl*8..sl*8+7. shfl_xor(16,32) reduce.
// ---------------------------------------------------------------------------
__global__ __launch_bounds__(256, 4) void gather_kernel(
    const unsigned short* __restrict__ featbf,
    const float4* __restrict__ ecoef,
    const int*   __restrict__ rowptr,
    const float* __restrict__ Wsp,   // [128][3]
    const float* __restrict__ bsp,   // [128]
    unsigned short* __restrict__ hmbf,  // [N][128]
    int N, int nwaves)
{
    int gw   = (blockIdx.x * 256 + threadIdx.x) >> 6;
    int lane = threadIdx.x & 63;
    int q    = lane >> 4;
    int sl   = lane & 15;
    int d    = sl * 8;

    // W rows d..d+7 = 24 consecutive floats (16B aligned: d%8==0)
    float wv[24];
    {
        const float4* w4 = (const float4*)(Wsp + d * 3);
#pragma unroll
        for (int t = 0; t < 6; ++t) *(float4*)&wv[t * 4] = w4[t];
    }
    float bvv[8];
    *(float4*)&bvv[0] = *(const float4*)(bsp + d);
    *(float4*)&bvv[4] = *(const float4*)(bsp + d + 4);

    for (int v = gw; v < N; v += nwaves) {
        int start = rowptr[v];
        int end   = rowptr[v + 1];

        float a[8];
#pragma unroll
        for (int j = 0; j < 8; ++j) a[j] = 0.f;

        for (int i = start + q; i < end; i += 4) {
            float4 qc = ecoef[i];
            int sv = __float_as_int(qc.w);
            bf16x8 f = *(const bf16x8*)(featbf + (size_t)sv * DIN + d);
#pragma unroll
            for (int j = 0; j < 8; ++j) {
                float g = fmaf(qc.x, wv[j * 3 + 0],
                          fmaf(qc.y, wv[j * 3 + 1],
                          fmaf(qc.z, wv[j * 3 + 2], bvv[j])));
                a[j] = fmaf(lrelu(g), bf2f((unsigned short)f[j]), a[j]);
            }
        }

#pragma unroll
        for (int j = 0; j < 8; ++j) {
            a[j] += __shfl_xor(a[j], 16);
            a[j] += __shfl_xor(a[j], 32);
        }

        if (q == 0) {
            float invd = 1.0f / fmaxf((float)(end - start), 1.0f);
            bf16x8 o;
#pragma unroll
            for (int j = 0; j < 8; ++j) o[j] = (short)f2bf(a[j] * invd);
            *(bf16x8*)(hmbf + (size_t)v * DIN + d) = o;
        }
    }
}

// ---------------------------------------------------------------------------
// 5) Node GEMM via MFMA: out = lrelu([featbf | hmbf] @ Wc^T + bb)
// ---------------------------------------------------------------------------
__global__ __launch_bounds__(256) void node_mfma_kernel(
    const unsigned short* __restrict__ featbf,
    const unsigned short* __restrict__ hmbf,
    const unsigned short* __restrict__ bfrag,
    const float* __restrict__ bb,
    float* __restrict__ out, int N)
{
    int wave = threadIdx.x >> 6;
    int lane = threadIdx.x & 63;
    int r0   = blockIdx.x * 64 + wave * 16;
    int row  = r0 + (lane & 15);
    bool rowok = row < N;
    int kb = (lane >> 4) << 3;

    f32x4 acc[8];
#pragma unroll
    for (int f = 0; f < 8; ++f) acc[f] = (f32x4)0.0f;

#pragma unroll
    for (int s = 0; s < 8; ++s) {
        bf16x8 a = (bf16x8)(short)0;
        if (rowok) {
            const unsigned short* base =
                (s < 4 ? featbf : hmbf) + (size_t)row * DIN + (s & 3) * 32 + kb;
            a = *(const bf16x8*)base;
        }
#pragma unroll
        for (int f = 0; f < 8; ++f) {
            bf16x8 b = *(const bf16x8*)(bfrag + ((((s * 8 + f) * 64) + lane) * 8));
            acc[f] = __builtin_amdgcn_mfma_f32_16x16x32_bf16(a, b, acc[f], 0, 0, 0);
        }
    }

    int crow = r0 + ((lane >> 4) << 2);
    int col  = lane & 15;
#pragma unroll
    for (int f = 0; f < 8; ++f) {
        int c = f * 16 + col;
        float bbv = bb[c];
#pragma unroll
        for (int r = 0; r < 4; ++r) {
            int rr = crow + r;
            if (rr < N) out[(size_t)rr * DOUT + c] = lrelu(acc[f][r] + bbv);
        }
    }
}

// ---------------------------------------------------------------------------
extern "C" void kernel_launch(void* const* d_in, const int* in_sizes, int n_in,
                              void* d_out, int out_size, void* d_ws, size_t ws_size,
                              hipStream_t stream)
{
    const float* feat    = (const float*)d_in[0];
    const float* pos     = (const float*)d_in[1];
    const int*   src     = (const int*)  d_in[2];
    const int*   dst     = (const int*)  d_in[3];
    const float* Wsp     = (const float*)d_in[4];
    const float* bsp     = (const float*)d_in[5];
    const float* Wneigh  = (const float*)d_in[6];
    const float* b_neigh = (const float*)d_in[7];
    const float* Wself   = (const float*)d_in[8];
    const float* b_self  = (const float*)d_in[9];
    const float* bias    = (const float*)d_in[10];

    int N = in_sizes[0] / DIN;
    int E = in_sizes[2];
    int nb = (N + 1023) / 1024;   // scan blocks (49 for N=50000; <= 64)

    // Workspace layout (all 16B aligned):
    // featbf [N*128 u16] | hmbf [N*128 u16] | ecoef [E f4] | bfrag [32768 u16]
    // | bb [128 f32] | hist [N] | cur [N] | rowptr [N+4] | bsum [64] | bbase [64]
    char* p = (char*)d_ws;
    unsigned short* featbf = (unsigned short*)p; p += (size_t)N * DIN * 2;
    unsigned short* hmbf   = (unsigned short*)p; p += (size_t)N * DIN * 2;
    float4* ecoef          = (float4*)p;         p += (size_t)E * 16;
    unsigned short* bfrag  = (unsigned short*)p; p += 32768 * 2;
    float* bb              = (float*)p;          p += 128 * 4;
    int* hist              = (int*)p;            p += (size_t)N * 4;
    int* cur               = (int*)p;            p += (size_t)N * 4;
    int* rowptr            = (int*)p;            p += (size_t)(N + 4) * 4;
    int* bsum              = (int*)p;            p += 64 * 4;
    int* bbase             = (int*)p;

    // zero hist + cur (adjacent)
    hipMemsetAsync(hist, 0, (size_t)2 * N * sizeof(int), stream);

    int eb = (E + 255) / 256;            // hist blocks
    int cb = (N * 16 + 255) / 256;       // convert blocks (N*128/8 threads)
    int pb = 129;                        // pack blocks
    prep_kernel<<<eb + cb + pb, 256, 0, stream>>>(
        dst, hist, E, eb, feat, featbf, N * 16, cb,
        Wself, Wneigh, b_self, b_neigh, bias, bfrag, bb);

    scan_part1<<<nb, 256, 0, stream>>>(hist, bsum, N);
    scan_part2<<<1, 64, 0, stream>>>(bsum, bbase, nb, rowptr, N, E);
    scan_part3<<<nb, 256, 0, stream>>>(hist, bbase, rowptr, N);

    scatter_kernel<<<eb, 256, 0, stream>>>(dst, src, pos, rowptr, cur, ecoef, E);

    int gblocks = 2048;
    gather_kernel<<<gblocks, 256, 0, stream>>>(featbf, ecoef, rowptr, Wsp, bsp,
                                               hmbf, N, gblocks * 4);

    node_mfma_kernel<<<(N + 63) / 64, 256, 0, stream>>>(featbf, hmbf, bfrag, bb,
                                                        (float*)d_out, N);
}